// Round 7
// baseline (59.927 us; speedup 1.0000x reference)
//
#include <hip/hip_runtime.h>
#include <cstddef>

#define L1n 128
#define L2n 256
#define Kn  1024
#define BK  64
#define NSTEP (Kn / BK)   // 16

using frag_ab = __attribute__((ext_vector_type(8))) short;  // 8 bf16
using frag_cd = __attribute__((ext_vector_type(4))) float;  // 4 f32

// RNE f32->bf16 pair pack (low, high)
__device__ __forceinline__ unsigned pack_bf16(float x, float y) {
    unsigned ux = __float_as_uint(x);
    ux = (ux + 0x7FFFu + ((ux >> 16) & 1u)) >> 16;
    unsigned uy = __float_as_uint(y);
    uy = (uy + 0x7FFFu + ((uy >> 16) & 1u)) & 0xFFFF0000u;
    return ux | uy;
}

// ---------------- Kernel 1: fused row-norm + bf16-MFMA GEMM + dist ----------------
// BYTE-EXACT revert to the R2 structure (the only config measured at ~25us):
// 256 threads (4 waves 2x2), 64x64 tile, BK=64, 1-deep prefetch issued after
// the barrier, non-swapped mfma(a,b), ROW-MAJOR dist[row][col] epilogue.
// R3/R5/R6 variants (transposed epilogue / 2-deep prefetch / K-split) all
// measured 40-43us with VALUBusy ~20%; this round isolates the R2 codegen.
__global__ __launch_bounds__(256) void gemm_dist_kernel(
    const float* __restrict__ seq1,
    const float* __restrict__ seq2,
    float* __restrict__ dist)
{
    __shared__ __align__(16) unsigned char sA[2][64 * 128];  // 64 rows x 128 B (64 bf16)
    __shared__ __align__(16) unsigned char sB[2][64 * 128];
    __shared__ float sInvA[64];
    __shared__ float sInvB[64];

    // bijective XCD-chunk swizzle (512 % 8 == 0)
    const int wg   = ((blockIdx.x & 7) << 6) + (blockIdx.x >> 3);
    const int b    = wg >> 3;
    const int mt   = (wg >> 2) & 1;
    const int nt   = wg & 3;
    const int t    = threadIdx.x;
    const int lane = t & 63;
    const int w    = t >> 6;
    const int wr   = w >> 1;
    const int wc   = w & 1;

    const int r = t >> 2;      // staging row 0..63
    const int j = t & 3;       // staging chunk 0..3

    const float4* pA = reinterpret_cast<const float4*>(
        seq1 + (size_t)b * (L1n * Kn) + (size_t)(mt * 64 + r) * Kn) + j;
    const float4* pB = reinterpret_cast<const float4*>(
        seq2 + (size_t)b * (L2n * Kn) + (size_t)(nt * 64 + r) * Kn) + j;

    const int swz = (r & 7) << 4;

    float ssA = 0.0f, ssB = 0.0f;
    frag_cd acc[2][2] = {};

    float4 av[4], bv[4];
#pragma unroll
    for (int i = 0; i < 4; ++i) { av[i] = pA[4 * i]; bv[i] = pB[4 * i]; }

    // stage step 0 into buf 0
#pragma unroll
    for (int i = 0; i < 4; ++i) {
        ssA += av[i].x * av[i].x + av[i].y * av[i].y + av[i].z * av[i].z + av[i].w * av[i].w;
        ssB += bv[i].x * bv[i].x + bv[i].y * bv[i].y + bv[i].z * bv[i].z + bv[i].w * bv[i].w;
        const int kb = (j + 4 * i) * 8;
        *reinterpret_cast<uint2*>(&sA[0][r * 128 + (kb ^ swz)]) =
            make_uint2(pack_bf16(av[i].x, av[i].y), pack_bf16(av[i].z, av[i].w));
        *reinterpret_cast<uint2*>(&sB[0][r * 128 + (kb ^ swz)]) =
            make_uint2(pack_bf16(bv[i].x, bv[i].y), pack_bf16(bv[i].z, bv[i].w));
    }

    for (int s = 0; s < NSTEP; ++s) {
        __syncthreads();
        const int cur = s & 1;

        // issue next step's global loads early (latency hides under MFMA)
        if (s + 1 < NSTEP) {
#pragma unroll
            for (int i = 0; i < 4; ++i) {
                av[i] = pA[(s + 1) * 16 + 4 * i];
                bv[i] = pB[(s + 1) * 16 + 4 * i];
            }
        }

        // compute on buf cur: 8 ds_read_b128 + 8 MFMA
#pragma unroll
        for (int kk = 0; kk < 2; ++kk) {
            const int kb = kk * 64 + ((lane >> 4) << 4);
            const int m0 = wr * 32 + (lane & 15);
            const int n0 = wc * 32 + (lane & 15);
            const int fswz = ((lane & 7) << 4);
            frag_ab a0 = *reinterpret_cast<const frag_ab*>(&sA[cur][m0 * 128 + (kb ^ fswz)]);
            frag_ab a1 = *reinterpret_cast<const frag_ab*>(&sA[cur][(m0 + 16) * 128 + (kb ^ fswz)]);
            frag_ab b0 = *reinterpret_cast<const frag_ab*>(&sB[cur][n0 * 128 + (kb ^ fswz)]);
            frag_ab b1 = *reinterpret_cast<const frag_ab*>(&sB[cur][(n0 + 16) * 128 + (kb ^ fswz)]);
            acc[0][0] = __builtin_amdgcn_mfma_f32_16x16x32_bf16(a0, b0, acc[0][0], 0, 0, 0);
            acc[0][1] = __builtin_amdgcn_mfma_f32_16x16x32_bf16(a0, b1, acc[0][1], 0, 0, 0);
            acc[1][0] = __builtin_amdgcn_mfma_f32_16x16x32_bf16(a1, b0, acc[1][0], 0, 0, 0);
            acc[1][1] = __builtin_amdgcn_mfma_f32_16x16x32_bf16(a1, b1, acc[1][1], 0, 0, 0);
        }

        // convert + write next step into the other buffer
        if (s + 1 < NSTEP) {
            const int nxt = cur ^ 1;
#pragma unroll
            for (int i = 0; i < 4; ++i) {
                ssA += av[i].x * av[i].x + av[i].y * av[i].y + av[i].z * av[i].z + av[i].w * av[i].w;
                ssB += bv[i].x * bv[i].x + bv[i].y * bv[i].y + bv[i].z * bv[i].z + bv[i].w * bv[i].w;
                const int kb = (j + 4 * i) * 8;
                *reinterpret_cast<uint2*>(&sA[nxt][r * 128 + (kb ^ swz)]) =
                    make_uint2(pack_bf16(av[i].x, av[i].y), pack_bf16(av[i].z, av[i].w));
                *reinterpret_cast<uint2*>(&sB[nxt][r * 128 + (kb ^ swz)]) =
                    make_uint2(pack_bf16(bv[i].x, bv[i].y), pack_bf16(bv[i].z, bv[i].w));
            }
        }
    }

    // full-row sum of squares: reduce across the 4 staging threads per row
    ssA += __shfl_xor(ssA, 1); ssA += __shfl_xor(ssA, 2);
    ssB += __shfl_xor(ssB, 1); ssB += __shfl_xor(ssB, 2);
    if (j == 0) { sInvA[r] = rsqrtf(ssA); sInvB[r] = rsqrtf(ssB); }
    __syncthreads();

    // epilogue: dist[b][row][col] = 1 - acc * invA[row] * invB[col]  (row-major, R2-exact)
    float* dbase = dist + (size_t)b * (L1n * L2n);
#pragma unroll
    for (int mi = 0; mi < 2; ++mi) {
#pragma unroll
        for (int nj = 0; nj < 2; ++nj) {
            const int row_l = wr * 32 + mi * 16 + ((lane >> 4) << 2);
            const int col_l = wc * 32 + nj * 16 + (lane & 15);
            const float ibv = sInvB[col_l];
            const int gcol = nt * 64 + col_l;
#pragma unroll
            for (int reg = 0; reg < 4; ++reg) {
                const int grow = mt * 64 + row_l + reg;
                dbase[(size_t)grow * L2n + gcol] =
                    1.0f - acc[mi][nj][reg] * sInvA[row_l + reg] * ibv;
            }
        }
    }
}

// ---------------- Kernel 2: DTW lag-skewed column sweep, global-direct ----------------
// Same structure as the R4 kernel (measured ~2.4us), adapted to ROW-MAJOR
// dist: lane l reads dist[2l][jj] and dist[2l+1][jj] as two scalar streams
// (L2/L3-resident; 16-deep x2 prefetch hides latency).
__global__ __launch_bounds__(64) void dtw_kernel(
    const float* __restrict__ dist, float* __restrict__ out)
{
    const int b    = blockIdx.x;
    const int lane = threadIdx.x;
    const float INF = 3.0e38f;
    const bool lane0 = (lane == 0);
    const float* base0 = dist + (size_t)b * (L1n * L2n) + (size_t)(2 * lane) * L2n;
    const float* base1 = base0 + L2n;

    float c0 = INF, c1 = INF;
    float sh0 = INF, sh1 = INF, sh2 = INF, sh3 = INF, sh4 = INF;

    auto ldval = [&](int tt) -> float2 {
        int jj = tt - 4 * lane;
        jj = jj < 0 ? 0 : (jj > L2n - 1 ? L2n - 1 : jj);
        return make_float2(base0[jj], base1[jj]);
    };

    auto step = [&](float2 d, bool t0) {
        float u = lane0 ? (t0 ? 0.0f : INF) : sh3;   // D(r0-1, jj)
        float g = lane0 ? INF : sh4;                  // D(r0-1, jj-1)
        float ugm = fminf(u, g);
        float n0 = d.x + fminf(c0, ugm);
        float n1 = d.y + fminf(fminf(c1, c0), n0);
        float snew = __shfl_up(n1, 1);
        sh4 = sh3; sh3 = sh2; sh2 = sh1; sh1 = sh0; sh0 = snew;
        c0 = n0; c1 = n1;
    };

    float2 pfA[8], pfB[8];
#pragma unroll
    for (int u = 0; u < 8; ++u) pfA[u] = ldval(u);
#pragma unroll
    for (int u = 0; u < 8; ++u) pfB[u] = ldval(8 + u);

#pragma unroll
    for (int u = 0; u < 8; ++u) step(pfA[u], u == 0);
#pragma unroll
    for (int u = 0; u < 8; ++u) pfA[u] = ldval(16 + u);

    int t = 8;
    for (int i = 0; i < 31; ++i) {    // t = 8 .. 503
        float2 curB[8];
#pragma unroll
        for (int u = 0; u < 8; ++u) curB[u] = pfB[u];
#pragma unroll
        for (int u = 0; u < 8; ++u) pfB[u] = ldval(t + 16 + u);
#pragma unroll
        for (int u = 0; u < 8; ++u) step(curB[u], false);

        float2 curA[8];
#pragma unroll
        for (int u = 0; u < 8; ++u) curA[u] = pfA[u];
#pragma unroll
        for (int u = 0; u < 8; ++u) pfA[u] = ldval(t + 24 + u);
#pragma unroll
        for (int u = 0; u < 8; ++u) step(curA[u], false);
        t += 16;
    }

#pragma unroll
    for (int u = 0; u < 4; ++u) step(pfB[u], false);

    // lane 63 finished (127,255) at t=507 -> c1
    if (lane == 63)
        out[b] = 1.0f / (1.0f + c1 * (1.0f / (float)(L1n + L2n)));
}

extern "C" void kernel_launch(void* const* d_in, const int* in_sizes, int n_in,
                              void* d_out, int out_size, void* d_ws, size_t ws_size,
                              hipStream_t stream) {
    const float* seq1 = (const float*)d_in[0];   // 64*128*1024 f32
    const float* seq2 = (const float*)d_in[1];   // 64*256*1024 f32
    float* out  = (float*)d_out;                 // 64 f32
    float* dist = (float*)d_ws;                  // 8 MB scratch (row-major dist)

    gemm_dist_kernel<<<dim3(512), dim3(256), 0, stream>>>(seq1, seq2, dist);
    dtw_kernel<<<dim3(64), dim3(64), 0, stream>>>(dist, out);
}